// Round 6
// baseline (1712.717 us; speedup 1.0000x reference)
//
#include <hip/hip_runtime.h>
#include <hip/hip_bf16.h>
#include <cstdint>

typedef __attribute__((ext_vector_type(8))) short short8;
typedef __attribute__((ext_vector_type(4))) float f32x4;
typedef __attribute__((ext_vector_type(4))) unsigned short ushort4v;

#define DEV static __device__ __forceinline__

DEV float bf2f(unsigned short u) {
    union { unsigned int i; float f; } v; v.i = ((unsigned int)u) << 16; return v.f;
}
DEV unsigned short f2bf(float f) {
    union { float f; unsigned int i; } v; v.f = f;
    unsigned int x = v.i;
    unsigned int r = x + 0x7fffu + ((x >> 16) & 1u);
    return (unsigned short)(r >> 16);
}

// ---------------------------------------------------------------------------
// GEMM: C[M,N] = A[M,K](bf16, row-stride lda) @ Wt[N,K]^T + bias -> bf16 (ldc)
// 128x128 tile, 4 waves, 16x16x32 MFMA, BK=64, single-buffer LDS (34.8KB ->
// 4 blocks/CU; inter-block overlap beats explicit dbuf at 2 blocks/CU,
// measured r2 65.5us vs r3 dbuf 75.9us).
// EPI 0: elu+1 applied iff col<512 | EPI 2: relu
// ---------------------------------------------------------------------------
template<int EPI>
__global__ __launch_bounds__(256) void gemm_kernel(
    const unsigned short* __restrict__ A, int lda,
    const unsigned short* __restrict__ Bt,
    const float* __restrict__ bias,
    unsigned short* __restrict__ outp, int ldc,
    int M, int N, int K)
{
    __shared__ unsigned short lds[128 * 136];
    const int t  = threadIdx.x;
    const int w  = t >> 6, l = t & 63;
    const int wr = w >> 1, wc = w & 1;
    const int lr = l & 15, lg = l >> 4;
    const long tM = (long)blockIdx.x * 128;
    const long tN = (long)blockIdx.y * 128;

    f32x4 acc[4][4];
#pragma unroll
    for (int i = 0; i < 4; i++)
#pragma unroll
        for (int j = 0; j < 4; j++) acc[i][j] = f32x4{0.f, 0.f, 0.f, 0.f};

    const unsigned short* Ab = A  + tM * lda;
    const unsigned short* Bb = Bt + tN * K;

    for (int kt = 0; kt < K; kt += 64) {
#pragma unroll
        for (int j = 0; j < 4; j++) {
            int c = (w * 4 + j) * 64 + l;
            int row = c >> 3, sc = (c & 7) ^ (row & 7);
            __builtin_amdgcn_global_load_lds(
                (const __attribute__((address_space(1))) void*)(Ab + (long)row * lda + kt + sc * 8),
                (__attribute__((address_space(3))) void*)(lds + (w * 4 + j) * 512),
                16, 0, 0);
        }
#pragma unroll
        for (int j = 0; j < 4; j++) {
            int c = (w * 4 + j) * 64 + l;
            int row = c >> 3, sc = (c & 7) ^ (row & 7);
            __builtin_amdgcn_global_load_lds(
                (const __attribute__((address_space(1))) void*)(Bb + (long)row * K + kt + sc * 8),
                (__attribute__((address_space(3))) void*)(lds + 8192 + (w * 4 + j) * 512),
                16, 0, 0);
        }
        __syncthreads();
#pragma unroll
        for (int kk = 0; kk < 2; kk++) {
            short8 af[4], bfv[4];
#pragma unroll
            for (int mi = 0; mi < 4; mi++) {
                int r  = wr * 64 + mi * 16 + lr;
                int kc = kk * 4 + lg;
                af[mi] = *(const short8*)&lds[r * 64 + ((kc ^ (r & 7)) << 3)];
            }
#pragma unroll
            for (int ni = 0; ni < 4; ni++) {
                int n  = wc * 64 + ni * 16 + lr;
                int kc = kk * 4 + lg;
                bfv[ni] = *(const short8*)&lds[8192 + n * 64 + ((kc ^ (n & 7)) << 3)];
            }
#pragma unroll
            for (int mi = 0; mi < 4; mi++)
#pragma unroll
                for (int ni = 0; ni < 4; ni++)
                    acc[mi][ni] = __builtin_amdgcn_mfma_f32_16x16x32_bf16(
                        af[mi], bfv[ni], acc[mi][ni], 0, 0, 0);
        }
        __syncthreads();
    }

    float bv[4];
#pragma unroll
    for (int ni = 0; ni < 4; ni++) bv[ni] = bias[tN + wc * 64 + ni * 16 + lr];
    const bool doElu = (EPI == 0) && (tN < 512);

#pragma unroll
    for (int mi = 0; mi < 4; mi++)
#pragma unroll
        for (int ni = 0; ni < 4; ni++)
#pragma unroll
            for (int j = 0; j < 4; j++) {
                float v = acc[mi][ni][j] + bv[ni];
                if (EPI == 0) { if (doElu) v = (v > 0.f) ? (v + 1.f) : expf(v); }
                if (EPI == 2) v = fmaxf(v, 0.f);
                int r = wr * 64 + mi * 16 + lg * 4 + j;
                int c = wc * 64 + ni * 16 + lr;
                lds[r * 136 + c] = f2bf(v);
            }
    __syncthreads();
#pragma unroll
    for (int i = 0; i < 8; i++) {
        int q = i * 256 + t;
        int r = q >> 4, cc = q & 15;
        short8 v8 = *(const short8*)&lds[r * 136 + cc * 8];
        *(short8*)&outp[(tM + r) * ldc + tN + cc * 8] = v8;
    }
}

// ---------------------------------------------------------------------------
// Fused GEMM + bias + residual(f32) + LayerNorm. BM=64, N=512 full row,
// 512 thr / 8 waves; wave w -> cols [w*64, w*64+64), acc 4x4 (64 f32).
// BK=64 with the PROVEN fat-gemm swizzle (64-short rows, sc=(c&7)^(row&7):
// zero bank conflicts measured). LDS 76.5KB -> 2 blocks/CU (16 waves/CU).
// y = LN(A@Wt^T + bias + res); writes y to f32 `of` and bf16 `ob`.
// res may alias of (per-elem read-before-write by owning thread).
// ---------------------------------------------------------------------------
__global__ __launch_bounds__(512, 4) void gemm_ln_kernel(
    const unsigned short* __restrict__ A, int lda,
    const unsigned short* __restrict__ Bt,   // [512][K]
    const float* __restrict__ bias,          // [512]
    const float* __restrict__ res,           // [M][512] f32
    const float* __restrict__ g,
    const float* __restrict__ be,
    float* __restrict__ of,                  // [M][512] f32
    unsigned short* __restrict__ ob,         // [M][512] bf16
    int K)
{
    __shared__ unsigned short sA[64 * 64];    // 8 KiB
    __shared__ unsigned short sB[512 * 64];   // 64 KiB
    __shared__ float red[2][8][64];           // 4 KiB
    __shared__ float stats[2][64];
    const int t = threadIdx.x, w = t >> 6, l = t & 63, lr = l & 15, lg = l >> 4;
    const long tM = (long)blockIdx.x * 64;

    f32x4 acc[4][4];
#pragma unroll
    for (int i = 0; i < 4; i++)
#pragma unroll
        for (int j = 0; j < 4; j++) acc[i][j] = f32x4{0.f, 0.f, 0.f, 0.f};

    const unsigned short* Ab = A + tM * lda;

    for (int kt = 0; kt < K; kt += 64) {
        {   // A: 64 rows x 8 chunks = 512 chunks, one per thread
            int c = t, row = c >> 3, sc = (c & 7) ^ (row & 7);
            __builtin_amdgcn_global_load_lds(
                (const __attribute__((address_space(1))) void*)(Ab + (long)row * lda + kt + sc * 8),
                (__attribute__((address_space(3))) void*)(sA + w * 512),
                16, 0, 0);
        }
#pragma unroll
        for (int j = 0; j < 8; j++) {  // B: 512 rows x 8 chunks = 4096 chunks
            int c = j * 512 + t, row = c >> 3, sc = (c & 7) ^ (row & 7);
            __builtin_amdgcn_global_load_lds(
                (const __attribute__((address_space(1))) void*)(Bt + (long)row * K + kt + sc * 8),
                (__attribute__((address_space(3))) void*)(sB + (j * 512 + w * 64) * 8),
                16, 0, 0);
        }
        __syncthreads();
#pragma unroll
        for (int kk = 0; kk < 2; kk++) {
            short8 av[4], bw[4];
#pragma unroll
            for (int mi = 0; mi < 4; mi++) {
                int r = mi * 16 + lr, kc = kk * 4 + lg;
                av[mi] = *(const short8*)&sA[r * 64 + ((kc ^ (r & 7)) << 3)];
            }
#pragma unroll
            for (int ni = 0; ni < 4; ni++) {
                int n = w * 64 + ni * 16 + lr, kc = kk * 4 + lg;
                bw[ni] = *(const short8*)&sB[n * 64 + ((kc ^ (n & 7)) << 3)];
            }
#pragma unroll
            for (int mi = 0; mi < 4; mi++)
#pragma unroll
                for (int ni = 0; ni < 4; ni++)
                    acc[mi][ni] = __builtin_amdgcn_mfma_f32_16x16x32_bf16(
                        av[mi], bw[ni], acc[mi][ni], 0, 0, 0);
        }
        __syncthreads();
    }

    // epilogue: v = C + bias + res; LN over the 512-wide row
    float gv[4], bev[4], bb[4];
#pragma unroll
    for (int ni = 0; ni < 4; ni++) {
        int col = w * 64 + ni * 16 + lr;
        gv[ni] = g[col]; bev[ni] = be[col]; bb[ni] = bias[col];
    }
#pragma unroll
    for (int mi = 0; mi < 4; mi++)
#pragma unroll
        for (int jj = 0; jj < 4; jj++) {
            long row = tM + mi * 16 + lg * 4 + jj;
#pragma unroll
            for (int ni = 0; ni < 4; ni++) {
                int col = w * 64 + ni * 16 + lr;
                acc[mi][ni][jj] += bb[ni] + res[row * 512 + col];
            }
        }
    // per-row partials: in-lane over ni, 16-lane butterfly over lr
#pragma unroll
    for (int mi = 0; mi < 4; mi++)
#pragma unroll
        for (int jj = 0; jj < 4; jj++) {
            float s = 0.f, ss = 0.f;
#pragma unroll
            for (int ni = 0; ni < 4; ni++) {
                float v = acc[mi][ni][jj];
                s += v; ss += v * v;
            }
#pragma unroll
            for (int off = 1; off < 16; off <<= 1) {
                s  += __shfl_xor(s, off);
                ss += __shfl_xor(ss, off);
            }
            if (lr == 0) {
                int rb = mi * 16 + lg * 4 + jj;
                red[0][w][rb] = s;
                red[1][w][rb] = ss;
            }
        }
    __syncthreads();
    if (t < 64) {
        float S = 0.f, SS = 0.f;
#pragma unroll
        for (int ww = 0; ww < 8; ww++) { S += red[0][ww][t]; SS += red[1][ww][t]; }
        float mean = S * (1.0f / 512.0f);
        float var  = SS * (1.0f / 512.0f) - mean * mean;
        stats[0][t] = mean;
        stats[1][t] = rsqrtf(fmaxf(var, 0.f) + 1e-5f);
    }
    __syncthreads();
#pragma unroll
    for (int mi = 0; mi < 4; mi++)
#pragma unroll
        for (int jj = 0; jj < 4; jj++) {
            int rb = mi * 16 + lg * 4 + jj;
            long row = tM + rb;
            float mean = stats[0][rb], rstd = stats[1][rb];
#pragma unroll
            for (int ni = 0; ni < 4; ni++) {
                int col = w * 64 + ni * 16 + lr;
                float y = (acc[mi][ni][jj] - mean) * rstd * gv[ni] + bev[ni];
                of[row * 512 + col] = y;
                ob[row * 512 + col] = f2bf(y);
            }
        }
}

// ---------------------------------------------------------------------------
// Attention glue. KVbuf[(s*8+b)][1024]: cols 0..511 = phiK (later ATTN),
// cols 512..1023 = V (later phiQ)
// ctx_partial also accumulates ksum_d = sum_s phiK[s][d] (part2).
// ---------------------------------------------------------------------------
__global__ __launch_bounds__(256) void ctx_partial_kernel(
    const unsigned short* __restrict__ kv, float* __restrict__ part,
    float* __restrict__ part2)
{
    const int p = blockIdx.x, ch = blockIdx.y;
    const int b = p >> 3, h = p & 7;
    __shared__ float kb[64 * 68];
    __shared__ float vbuf[64 * 68];
    const int t = threadIdx.x;
    const int dq = t >> 4, eq = t & 15;
    f32x4 acc[4];
    f32x4 ks = {0.f, 0.f, 0.f, 0.f};
#pragma unroll
    for (int i = 0; i < 4; i++) acc[i] = f32x4{0.f, 0.f, 0.f, 0.f};

    for (int sub = 0; sub < 8; sub++) {
        int sbase = ch * 512 + sub * 64;
#pragma unroll
        for (int i = 0; i < 2; i++) {
            int idx = i * 256 + t;
            int row = idx >> 3, c8 = idx & 7;
            long ga = ((long)(sbase + row) * 8 + b) * 1024 + h * 64 + c8 * 8;
            short8 kvv = *(const short8*)&kv[ga];
            short8 vv  = *(const short8*)&kv[ga + 512];
#pragma unroll
            for (int j = 0; j < 8; j++) {
                kb[row * 68 + c8 * 8 + j]   = bf2f((unsigned short)kvv[j]);
                vbuf[row * 68 + c8 * 8 + j] = bf2f((unsigned short)vv[j]);
            }
        }
        __syncthreads();
        for (int s = 0; s < 64; s++) {
            f32x4 k4 = *(const f32x4*)&kb[s * 68 + dq * 4];
            f32x4 v4 = *(const f32x4*)&vbuf[s * 68 + eq * 4];
#pragma unroll
            for (int i = 0; i < 4; i++) acc[i] += k4[i] * v4;
            ks += k4;
        }
        __syncthreads();
    }
    float* o = part + (long)(p * 8 + ch) * 4096;
#pragma unroll
    for (int i = 0; i < 4; i++)
        *(f32x4*)&o[(dq * 4 + i) * 64 + eq * 4] = acc[i];
    if (eq == 0)
        *(f32x4*)&part2[(p * 8 + ch) * 64 + dq * 4] = ks;
}

// reduce ctx partials -> ctxA[p][n=e][k=d] (bf16, transposed); also finalize
// ksum into row n=64 and zero rows n=65..79
__global__ __launch_bounds__(256) void ctx_reduce_kernel(
    const float* __restrict__ part, const float* __restrict__ part2,
    unsigned short* __restrict__ ctxA)
{
    int o = (blockIdx.x * 256 + threadIdx.x) * 4;
    int p = o >> 12, d = (o >> 6) & 63, e0 = o & 63;
    f32x4 s = {0.f, 0.f, 0.f, 0.f};
    for (int ch = 0; ch < 8; ch++)
        s += *(const f32x4*)&part[(long)(p * 8 + ch) * 4096 + d * 64 + e0];
#pragma unroll
    for (int j = 0; j < 4; j++) ctxA[p * 5120 + (e0 + j) * 64 + d] = f2bf(s[j]);
    if (e0 == 0) {
        float ksv = 0.f;
#pragma unroll
        for (int ch = 0; ch < 8; ch++) ksv += part2[(p * 8 + ch) * 64 + d];
        ctxA[p * 5120 + 4096 + d] = f2bf(ksv);
#pragma unroll
        for (int j = 1; j < 16; j++) ctxA[p * 5120 + 4096 + j * 64 + d] = 0;
    }
}

// out = phiQ @ [ctx | ksum]; ni=4 accumulates denominator; normalize -> bf16
__global__ __launch_bounds__(256) void attn_out_kernel(
    unsigned short* __restrict__ kv,
    const unsigned short* __restrict__ ctxA)
{
    const int p = blockIdx.x;
    const int b = p >> 3, h = p & 7;
    const int t = threadIdx.x, w = t >> 6, l = t & 63, lr = l & 15, lg = l >> 4;
    const int s0 = blockIdx.y * 256 + w * 64;
    f32x4 acc[4][5];
#pragma unroll
    for (int i = 0; i < 4; i++)
#pragma unroll
        for (int j = 0; j < 5; j++) acc[i][j] = f32x4{0.f, 0.f, 0.f, 0.f};
    const unsigned short* cb = ctxA + p * 5120;
#pragma unroll
    for (int kk = 0; kk < 2; kk++) {
        short8 af[4], bfv[5];
#pragma unroll
        for (int mi = 0; mi < 4; mi++) {
            int s = s0 + mi * 16 + lr;
            af[mi] = *(const short8*)&kv[((long)s * 8 + b) * 1024 + 512 + h * 64 + kk * 32 + lg * 8];
        }
#pragma unroll
        for (int ni = 0; ni < 5; ni++)
            bfv[ni] = *(const short8*)&cb[(ni * 16 + lr) * 64 + kk * 32 + lg * 8];
#pragma unroll
        for (int mi = 0; mi < 4; mi++)
#pragma unroll
            for (int ni = 0; ni < 5; ni++)
                acc[mi][ni] = __builtin_amdgcn_mfma_f32_16x16x32_bf16(
                    af[mi], bfv[ni], acc[mi][ni], 0, 0, 0);
    }
#pragma unroll
    for (int mi = 0; mi < 4; mi++) {
#pragma unroll
        for (int j = 0; j < 4; j++) {
            float den = __shfl(acc[mi][4][j], (l & 48));
            float rc  = 1.0f / (den + 1e-6f);
            int s = s0 + mi * 16 + lg * 4 + j;
            long base = ((long)s * 8 + b) * 1024 + h * 64;
#pragma unroll
            for (int ni = 0; ni < 4; ni++)
                kv[base + ni * 16 + lr] = f2bf(acc[mi][ni][j] * rc);
        }
    }
}

// ---------------------------------------------------------------------------
// small helpers
// ---------------------------------------------------------------------------
__global__ __launch_bounds__(256) void cvtbf_kernel(
    const float* __restrict__ x, unsigned short* __restrict__ y)
{
    long i = ((long)blockIdx.x * 256 + threadIdx.x) * 8;
    f32x4 a = *(const f32x4*)&x[i];
    f32x4 c = *(const f32x4*)&x[i + 4];
    short8 pk;
#pragma unroll
    for (int j = 0; j < 4; j++) { pk[j] = (short)f2bf(a[j]); pk[4 + j] = (short)f2bf(c[j]); }
    *(short8*)&y[i] = pk;
}

__global__ __launch_bounds__(256) void bcat_kernel(
    const float* __restrict__ bk, const float* __restrict__ bv, float* __restrict__ dst)
{
    int lyr = blockIdx.x;
    int j = blockIdx.y * 256 + threadIdx.x;
    dst[lyr * 1024 + j] = (j < 512) ? bk[lyr * 512 + j] : bv[lyr * 512 + j - 512];
}

// weight transpose + convert: Wt[n][k] = (bf16) W[k][n], per-layer strides
__global__ __launch_bounds__(256) void wconv_kernel(
    const float* __restrict__ W, unsigned short* __restrict__ Wt, int K, int N,
    long lstrW, long lstrT)
{
    __shared__ float tile[64 * 65];
    const long lz = blockIdx.z;
    const float* Wl = W + lz * lstrW;
    unsigned short* Wtl = Wt + lz * lstrT;
    const int k0 = blockIdx.x * 64, n0 = blockIdx.y * 64;
    const int t = threadIdx.x;
#pragma unroll
    for (int i = 0; i < 4; i++) {
        int q = i * 256 + t;
        int r = q >> 4, c4 = q & 15;
        f32x4 v = *(const f32x4*)&Wl[(long)(k0 + r) * N + n0 + c4 * 4];
#pragma unroll
        for (int j = 0; j < 4; j++) tile[r * 65 + c4 * 4 + j] = v[j];
    }
    __syncthreads();
#pragma unroll
    for (int i = 0; i < 4; i++) {
        int q = i * 256 + t;
        int nr = q >> 4, kc = q & 15;
        ushort4v pk;
#pragma unroll
        for (int j = 0; j < 4; j++) pk[j] = f2bf(tile[(kc * 4 + j) * 65 + nr]);
        *(ushort4v*)&Wtl[(long)(n0 + nr) * K + k0 + kc * 4] = pk;
    }
}

// ---------------------------------------------------------------------------
// Host orchestration.  ws ~121 MiB:
//  [WKV 4M][WQ 2M][WO 2M][W1 4M][W2 4M][BKV 16K][R1 32M][KV 64M][KSP][CTP 8M][CTA]
// f32 residual stream F1 = d_out (in-place RMW in gemm_ln; final LN2 leaves
// the answer there). R1 = bf16 copy of the stream (GEMM inputs).
// KV: {K|V} -> {ATTN|phiQ} -> HBF(64M).
// ---------------------------------------------------------------------------
extern "C" void kernel_launch(void* const* d_in, const int* in_sizes, int n_in,
                              void* d_out, int out_size, void* d_ws, size_t ws_size,
                              hipStream_t stream)
{
    const float* src  = (const float*)d_in[0];
    const float* Wq   = (const float*)d_in[1];
    const float* bq   = (const float*)d_in[2];
    const float* Wk   = (const float*)d_in[3];
    const float* bk   = (const float*)d_in[4];
    const float* Wv   = (const float*)d_in[5];
    const float* bv   = (const float*)d_in[6];
    const float* Wo   = (const float*)d_in[7];
    const float* bo   = (const float*)d_in[8];
    const float* l1g  = (const float*)d_in[9];
    const float* l1b  = (const float*)d_in[10];
    const float* W1   = (const float*)d_in[11];
    const float* b1   = (const float*)d_in[12];
    const float* W2   = (const float*)d_in[13];
    const float* b2   = (const float*)d_in[14];
    const float* l2g  = (const float*)d_in[15];
    const float* l2b  = (const float*)d_in[16];

    char* ws = (char*)d_ws;
    constexpr size_t SZ_WKV = (size_t)4 * 1024 * 512 * 2;
    constexpr size_t SZ_WQ  = (size_t)4 * 512 * 512 * 2;
    constexpr size_t SZ_WO  = SZ_WQ;
    constexpr size_t SZ_W1  = (size_t)4 * 512 * 1024 * 2;
    constexpr size_t SZ_W2  = SZ_W1;
    constexpr size_t SZ_BKV = (size_t)4 * 1024 * 4;
    constexpr size_t SZ_R1  = (size_t)32768 * 512 * 2;
    constexpr size_t SZ_KV  = (size_t)32768 * 1024 * 2;
    constexpr size_t OFF_WKV = 0;
    constexpr size_t OFF_WQ  = OFF_WKV + SZ_WKV;
    constexpr size_t OFF_WO  = OFF_WQ + SZ_WQ;
    constexpr size_t OFF_W1  = OFF_WO + SZ_WO;
    constexpr size_t OFF_W2  = OFF_W1 + SZ_W1;
    constexpr size_t OFF_BKV = OFF_W2 + SZ_W2;
    constexpr size_t OFF_R1  = OFF_BKV + SZ_BKV;
    constexpr size_t OFF_KV  = OFF_R1 + SZ_R1;
    constexpr size_t OFF_KSP = OFF_KV + SZ_KV;
    constexpr size_t OFF_CTP = OFF_KSP + (size_t)16 * 4096 * 4;
    constexpr size_t OFF_CTA = OFF_CTP + (size_t)64 * 8 * 4096 * 4;

    unsigned short* WKVT = (unsigned short*)(ws + OFF_WKV);
    unsigned short* WQT  = (unsigned short*)(ws + OFF_WQ);
    unsigned short* WOT  = (unsigned short*)(ws + OFF_WO);
    unsigned short* W1T  = (unsigned short*)(ws + OFF_W1);
    unsigned short* W2T  = (unsigned short*)(ws + OFF_W2);
    float*          BKV  = (float*)(ws + OFF_BKV);
    unsigned short* R1   = (unsigned short*)(ws + OFF_R1);   // bf16 stream copy
    unsigned short* KV   = (unsigned short*)(ws + OFF_KV);
    float*          KSP  = (float*)(ws + OFF_KSP);           // ksum partials (128KB)
    float*          CTP  = (float*)(ws + OFF_CTP);
    unsigned short* CTA  = (unsigned short*)(ws + OFF_CTA);
    float*          F1   = (float*)d_out;                    // f32 residual stream

    dim3 blk(256);
    wconv_kernel<<<dim3(8, 8, 4),  blk, 0, stream>>>(Wk, WKVT,            512, 512, 512*512, 1024*512);
    wconv_kernel<<<dim3(8, 8, 4),  blk, 0, stream>>>(Wv, WKVT + 512*512,  512, 512, 512*512, 1024*512);
    wconv_kernel<<<dim3(8, 8, 4),  blk, 0, stream>>>(Wq, WQT,             512, 512, 512*512, 512*512);
    wconv_kernel<<<dim3(8, 8, 4),  blk, 0, stream>>>(Wo, WOT,             512, 512, 512*512, 512*512);
    wconv_kernel<<<dim3(8, 16, 4), blk, 0, stream>>>(W1, W1T,             512, 1024, 512*1024, 512*1024);
    wconv_kernel<<<dim3(16, 8, 4), blk, 0, stream>>>(W2, W2T,             1024, 512, 1024*512, 1024*512);
    bcat_kernel<<<dim3(4, 4), blk, 0, stream>>>(bk, bv, BKV);
    cvtbf_kernel<<<8192, blk, 0, stream>>>(src, R1);

    for (int lyr = 0; lyr < 4; lyr++) {
        const unsigned short* wkvt = WKVT + (size_t)lyr * 1024 * 512;
        const unsigned short* wqt  = WQT  + (size_t)lyr * 512 * 512;
        const unsigned short* wot  = WOT  + (size_t)lyr * 512 * 512;
        const unsigned short* w1t  = W1T  + (size_t)lyr * 512 * 1024;
        const unsigned short* w2t  = W2T  + (size_t)lyr * 1024 * 512;

        // K|V fused GEMM (elu on cols<512)
        gemm_kernel<0><<<dim3(256, 8), blk, 0, stream>>>(R1, 512, wkvt, BKV + lyr * 1024, KV, 1024, 32768, 1024, 512);

        // ctx + ksum in one pass over KV
        ctx_partial_kernel<<<dim3(64, 8), blk, 0, stream>>>(KV, CTP, KSP);
        ctx_reduce_kernel<<<256, blk, 0, stream>>>(CTP, KSP, CTA);

        // phiQ into V slot (dead), ATTN into K slot (dead)
        gemm_kernel<0><<<dim3(256, 4), blk, 0, stream>>>(R1, 512, wqt, bq + lyr * 512, KV + 512, 1024, 32768, 512, 512);
        attn_out_kernel<<<dim3(64, 16), blk, 0, stream>>>(KV, CTA);

        // Wo + residual + LN1 -> F1(f32) in-place, bf16 to R1
        const float* resp = (lyr == 0) ? src : F1;
        gemm_ln_kernel<<<512, dim3(512), 0, stream>>>(KV, 1024, wot, bo + lyr * 512, resp,
                                                      l1g + lyr * 512, l1b + lyr * 512,
                                                      F1, R1, 512);
        // FFN up + relu -> HBF (KV region, dead)
        gemm_kernel<2><<<dim3(256, 8), blk, 0, stream>>>(R1, 512, w1t, b1 + lyr * 1024, KV, 1024, 32768, 1024, 512);
        // FFN down + residual + LN2 -> F1 in-place, bf16 to R1 (next XBF)
        gemm_ln_kernel<<<512, dim3(512), 0, stream>>>(KV, 1024, w2t, b2 + lyr * 512, F1,
                                                      l2g + lyr * 512, l2b + lyr * 512,
                                                      F1, R1, 1024);
    }
}

// Round 7
// 1320.089 us; speedup vs baseline: 1.2974x; 1.2974x over previous
//
#include <hip/hip_runtime.h>
#include <hip/hip_bf16.h>
#include <cstdint>

typedef __attribute__((ext_vector_type(8))) short short8;
typedef __attribute__((ext_vector_type(4))) float f32x4;
typedef __attribute__((ext_vector_type(4))) unsigned short ushort4v;

#define DEV static __device__ __forceinline__

DEV float bf2f(unsigned short u) {
    union { unsigned int i; float f; } v; v.i = ((unsigned int)u) << 16; return v.f;
}
DEV unsigned short f2bf(float f) {
    union { float f; unsigned int i; } v; v.f = f;
    unsigned int x = v.i;
    unsigned int r = x + 0x7fffu + ((x >> 16) & 1u);
    return (unsigned short)(r >> 16);
}

// ---------------------------------------------------------------------------
// GEMM: C[M,N] = A[M,K](bf16, row-stride lda) @ Wt[N,K]^T + bias -> bf16 (ldc)
// 128x128 tile, 4 waves, 16x16x32 MFMA, BK=64, single-buffer LDS (34.8KB ->
// 4 blocks/CU; measured best r2: 65.5us).
// 1D grid = 256*nby blocks with XCD-aware swizzle: the nby blocks sharing an
// A-tile are consecutive within one XCD's round-robin sequence -> A-tile is
// fetched once from HBM per XCD-group instead of nby times (r6 FETCH showed
// 104MB vs ~35MB ideal = 3x A over-fetch).
// EPI 0: elu+1 applied iff col<512 | EPI 2: relu
// ---------------------------------------------------------------------------
template<int EPI>
__global__ __launch_bounds__(256) void gemm_kernel(
    const unsigned short* __restrict__ A, int lda,
    const unsigned short* __restrict__ Bt,
    const float* __restrict__ bias,
    unsigned short* __restrict__ outp, int ldc,
    int nshift, int K)
{
    __shared__ unsigned short lds[128 * 136];
    const int t  = threadIdx.x;
    const int w  = t >> 6, l = t & 63;
    const int wr = w >> 1, wc = w & 1;
    const int lr = l & 15, lg = l >> 4;
    // XCD swizzle: consecutive bids round-robin XCDs; blocks {j, j+8, ...}
    // share an XCD. Give each XCD a contiguous x-range so same-A blocks
    // are XCD-local and back-to-back.
    const int bid = blockIdx.x;
    const int j8  = bid & 7, s = bid >> 3;
    const int bx  = j8 * 32 + (s >> nshift);
    const int by  = s & ((1 << nshift) - 1);
    const long tM = (long)bx * 128;
    const long tN = (long)by * 128;

    f32x4 acc[4][4];
#pragma unroll
    for (int i = 0; i < 4; i++)
#pragma unroll
        for (int j = 0; j < 4; j++) acc[i][j] = f32x4{0.f, 0.f, 0.f, 0.f};

    const unsigned short* Ab = A  + tM * lda;
    const unsigned short* Bb = Bt + tN * K;

    for (int kt = 0; kt < K; kt += 64) {
#pragma unroll
        for (int j = 0; j < 4; j++) {
            int c = (w * 4 + j) * 64 + l;
            int row = c >> 3, sc = (c & 7) ^ (row & 7);
            __builtin_amdgcn_global_load_lds(
                (const __attribute__((address_space(1))) void*)(Ab + (long)row * lda + kt + sc * 8),
                (__attribute__((address_space(3))) void*)(lds + (w * 4 + j) * 512),
                16, 0, 0);
        }
#pragma unroll
        for (int j = 0; j < 4; j++) {
            int c = (w * 4 + j) * 64 + l;
            int row = c >> 3, sc = (c & 7) ^ (row & 7);
            __builtin_amdgcn_global_load_lds(
                (const __attribute__((address_space(1))) void*)(Bb + (long)row * K + kt + sc * 8),
                (__attribute__((address_space(3))) void*)(lds + 8192 + (w * 4 + j) * 512),
                16, 0, 0);
        }
        __syncthreads();
#pragma unroll
        for (int kk = 0; kk < 2; kk++) {
            short8 af[4], bfv[4];
#pragma unroll
            for (int mi = 0; mi < 4; mi++) {
                int r  = wr * 64 + mi * 16 + lr;
                int kc = kk * 4 + lg;
                af[mi] = *(const short8*)&lds[r * 64 + ((kc ^ (r & 7)) << 3)];
            }
#pragma unroll
            for (int ni = 0; ni < 4; ni++) {
                int n  = wc * 64 + ni * 16 + lr;
                int kc = kk * 4 + lg;
                bfv[ni] = *(const short8*)&lds[8192 + n * 64 + ((kc ^ (n & 7)) << 3)];
            }
#pragma unroll
            for (int mi = 0; mi < 4; mi++)
#pragma unroll
                for (int ni = 0; ni < 4; ni++)
                    acc[mi][ni] = __builtin_amdgcn_mfma_f32_16x16x32_bf16(
                        af[mi], bfv[ni], acc[mi][ni], 0, 0, 0);
        }
        __syncthreads();
    }

    float bv[4];
#pragma unroll
    for (int ni = 0; ni < 4; ni++) bv[ni] = bias[tN + wc * 64 + ni * 16 + lr];
    const bool doElu = (EPI == 0) && (tN < 512);

#pragma unroll
    for (int mi = 0; mi < 4; mi++)
#pragma unroll
        for (int ni = 0; ni < 4; ni++)
#pragma unroll
            for (int j = 0; j < 4; j++) {
                float v = acc[mi][ni][j] + bv[ni];
                if (EPI == 0) { if (doElu) v = (v > 0.f) ? (v + 1.f) : expf(v); }
                if (EPI == 2) v = fmaxf(v, 0.f);
                int r = wr * 64 + mi * 16 + lg * 4 + j;
                int c = wc * 64 + ni * 16 + lr;
                lds[r * 136 + c] = f2bf(v);
            }
    __syncthreads();
#pragma unroll
    for (int i = 0; i < 8; i++) {
        int q = i * 256 + t;
        int r = q >> 4, cc = q & 15;
        short8 v8 = *(const short8*)&lds[r * 136 + cc * 8];
        *(short8*)&outp[(tM + r) * ldc + tN + cc * 8] = v8;
    }
}

// ---------------------------------------------------------------------------
// Fused GEMM + bias + residual(f32) + LayerNorm (r4-proven: 83us @K=1024).
// BM=128, 512 thr / 8 waves; wave (wr,wc): rows wr*64+[0,64), cols
// wc*128+[0,128). BK=64, fat-gemm swizzle (0 bank conflicts). Grid 256 = 1/CU.
// y = LN(A@Wt^T + bias + res); writes y to f32 `of` and bf16 `ob`.
// res may alias of (per-elem read-before-write by owning thread).
// ---------------------------------------------------------------------------
__global__ __launch_bounds__(512) void gemm_ln_kernel(
    const unsigned short* __restrict__ A, int lda,
    const unsigned short* __restrict__ Bt,   // [512][K]
    const float* __restrict__ bias,          // [512]
    const float* __restrict__ res,           // [M][512] f32
    const float* __restrict__ g,
    const float* __restrict__ be,
    float* __restrict__ of,                  // [M][512] f32
    unsigned short* __restrict__ ob,         // [M][512] bf16
    int K)
{
    __shared__ unsigned short sA[128 * 64];   // 16 KiB
    __shared__ unsigned short sB[512 * 64];   // 64 KiB
    __shared__ float red[2][4][128];
    __shared__ float stats[2][128];
    const int t = threadIdx.x, w = t >> 6, l = t & 63, lr = l & 15, lg = l >> 4;
    const int wr = w >> 2, wc = w & 3;
    const long tM = (long)blockIdx.x * 128;

    f32x4 acc[4][8];
#pragma unroll
    for (int i = 0; i < 4; i++)
#pragma unroll
        for (int j = 0; j < 8; j++) acc[i][j] = f32x4{0.f, 0.f, 0.f, 0.f};

    const unsigned short* Ab = A + tM * lda;

    for (int kt = 0; kt < K; kt += 64) {
#pragma unroll
        for (int j = 0; j < 2; j++) {
            int c = j * 512 + t;                // 128 rows x 8 chunks
            int row = c >> 3, sc = (c & 7) ^ (row & 7);
            __builtin_amdgcn_global_load_lds(
                (const __attribute__((address_space(1))) void*)(Ab + (long)row * lda + kt + sc * 8),
                (__attribute__((address_space(3))) void*)(sA + (j * 512 + w * 64) * 8),
                16, 0, 0);
        }
#pragma unroll
        for (int j = 0; j < 8; j++) {           // 512 rows x 8 chunks
            int c = j * 512 + t;
            int row = c >> 3, sc = (c & 7) ^ (row & 7);
            __builtin_amdgcn_global_load_lds(
                (const __attribute__((address_space(1))) void*)(Bt + (long)row * K + kt + sc * 8),
                (__attribute__((address_space(3))) void*)(sB + (j * 512 + w * 64) * 8),
                16, 0, 0);
        }
        __syncthreads();
#pragma unroll
        for (int kk = 0; kk < 2; kk++) {
            short8 av[4], bw[8];
#pragma unroll
            for (int mi = 0; mi < 4; mi++) {
                int r = wr * 64 + mi * 16 + lr, kc = kk * 4 + lg;
                av[mi] = *(const short8*)&sA[r * 64 + ((kc ^ (r & 7)) << 3)];
            }
#pragma unroll
            for (int ni = 0; ni < 8; ni++) {
                int n = wc * 128 + ni * 16 + lr, kc = kk * 4 + lg;
                bw[ni] = *(const short8*)&sB[n * 64 + ((kc ^ (n & 7)) << 3)];
            }
#pragma unroll
            for (int mi = 0; mi < 4; mi++)
#pragma unroll
                for (int ni = 0; ni < 8; ni++)
                    acc[mi][ni] = __builtin_amdgcn_mfma_f32_16x16x32_bf16(
                        av[mi], bw[ni], acc[mi][ni], 0, 0, 0);
        }
        __syncthreads();
    }

    // epilogue: v = C + bias + res; LN over the 512-wide row
    float gv[8], bev[8], bb[8];
#pragma unroll
    for (int ni = 0; ni < 8; ni++) {
        int col = wc * 128 + ni * 16 + lr;
        gv[ni] = g[col]; bev[ni] = be[col]; bb[ni] = bias[col];
    }
#pragma unroll
    for (int mi = 0; mi < 4; mi++)
#pragma unroll
        for (int jj = 0; jj < 4; jj++) {
            long row = tM + wr * 64 + mi * 16 + lg * 4 + jj;
#pragma unroll
            for (int ni = 0; ni < 8; ni++) {
                int col = wc * 128 + ni * 16 + lr;
                acc[mi][ni][jj] += bb[ni] + res[row * 512 + col];
            }
        }
    float s2[4][4], ss2[4][4];
#pragma unroll
    for (int mi = 0; mi < 4; mi++)
#pragma unroll
        for (int jj = 0; jj < 4; jj++) {
            float s = 0.f, ss = 0.f;
#pragma unroll
            for (int ni = 0; ni < 8; ni++) {
                float v = acc[mi][ni][jj];
                s += v; ss += v * v;
            }
#pragma unroll
            for (int off = 1; off < 16; off <<= 1) {
                s  += __shfl_xor(s, off);
                ss += __shfl_xor(ss, off);
            }
            s2[mi][jj] = s; ss2[mi][jj] = ss;
        }
    if (lr == 0) {
#pragma unroll
        for (int mi = 0; mi < 4; mi++)
#pragma unroll
            for (int jj = 0; jj < 4; jj++) {
                int rb = wr * 64 + mi * 16 + lg * 4 + jj;
                red[0][wc][rb] = s2[mi][jj];
                red[1][wc][rb] = ss2[mi][jj];
            }
    }
    __syncthreads();
    if (t < 128) {
        float S  = red[0][0][t] + red[0][1][t] + red[0][2][t] + red[0][3][t];
        float SS = red[1][0][t] + red[1][1][t] + red[1][2][t] + red[1][3][t];
        float mean = S * (1.0f / 512.0f);
        float var  = SS * (1.0f / 512.0f) - mean * mean;
        stats[0][t] = mean;
        stats[1][t] = rsqrtf(fmaxf(var, 0.f) + 1e-5f);
    }
    __syncthreads();
#pragma unroll
    for (int mi = 0; mi < 4; mi++)
#pragma unroll
        for (int jj = 0; jj < 4; jj++) {
            int rb = wr * 64 + mi * 16 + lg * 4 + jj;
            long row = tM + rb;
            float mean = stats[0][rb], rstd = stats[1][rb];
#pragma unroll
            for (int ni = 0; ni < 8; ni++) {
                int col = wc * 128 + ni * 16 + lr;
                float y = (acc[mi][ni][jj] - mean) * rstd * gv[ni] + bev[ni];
                of[row * 512 + col] = y;
                ob[row * 512 + col] = f2bf(y);
            }
        }
}

// ---------------------------------------------------------------------------
// Attention glue. KVbuf[(s*8+b)][1024]: cols 0..511 = phiK (later ATTN),
// cols 512..1023 = V (later phiQ).
// ctx_partial also accumulates ksum_d = sum_s phiK[s][d] (part2).
// ---------------------------------------------------------------------------
__global__ __launch_bounds__(256) void ctx_partial_kernel(
    const unsigned short* __restrict__ kv, float* __restrict__ part,
    float* __restrict__ part2)
{
    const int p = blockIdx.x, ch = blockIdx.y;
    const int b = p >> 3, h = p & 7;
    __shared__ float kb[64 * 68];
    __shared__ float vbuf[64 * 68];
    const int t = threadIdx.x;
    const int dq = t >> 4, eq = t & 15;
    f32x4 acc[4];
    f32x4 ks = {0.f, 0.f, 0.f, 0.f};
#pragma unroll
    for (int i = 0; i < 4; i++) acc[i] = f32x4{0.f, 0.f, 0.f, 0.f};

    for (int sub = 0; sub < 8; sub++) {
        int sbase = ch * 512 + sub * 64;
#pragma unroll
        for (int i = 0; i < 2; i++) {
            int idx = i * 256 + t;
            int row = idx >> 3, c8 = idx & 7;
            long ga = ((long)(sbase + row) * 8 + b) * 1024 + h * 64 + c8 * 8;
            short8 kvv = *(const short8*)&kv[ga];
            short8 vv  = *(const short8*)&kv[ga + 512];
#pragma unroll
            for (int j = 0; j < 8; j++) {
                kb[row * 68 + c8 * 8 + j]   = bf2f((unsigned short)kvv[j]);
                vbuf[row * 68 + c8 * 8 + j] = bf2f((unsigned short)vv[j]);
            }
        }
        __syncthreads();
        for (int s = 0; s < 64; s++) {
            f32x4 k4 = *(const f32x4*)&kb[s * 68 + dq * 4];
            f32x4 v4 = *(const f32x4*)&vbuf[s * 68 + eq * 4];
#pragma unroll
            for (int i = 0; i < 4; i++) acc[i] += k4[i] * v4;
            ks += k4;
        }
        __syncthreads();
    }
    float* o = part + (long)(p * 8 + ch) * 4096;
#pragma unroll
    for (int i = 0; i < 4; i++)
        *(f32x4*)&o[(dq * 4 + i) * 64 + eq * 4] = acc[i];
    if (eq == 0)
        *(f32x4*)&part2[(p * 8 + ch) * 64 + dq * 4] = ks;
}

// reduce ctx partials -> ctxA[p][n=e][k=d] (bf16, transposed); finalize ksum
// into row n=64, zero rows 65..79
__global__ __launch_bounds__(256) void ctx_reduce_kernel(
    const float* __restrict__ part, const float* __restrict__ part2,
    unsigned short* __restrict__ ctxA)
{
    int o = (blockIdx.x * 256 + threadIdx.x) * 4;
    int p = o >> 12, d = (o >> 6) & 63, e0 = o & 63;
    f32x4 s = {0.f, 0.f, 0.f, 0.f};
    for (int ch = 0; ch < 8; ch++)
        s += *(const f32x4*)&part[(long)(p * 8 + ch) * 4096 + d * 64 + e0];
#pragma unroll
    for (int j = 0; j < 4; j++) ctxA[p * 5120 + (e0 + j) * 64 + d] = f2bf(s[j]);
    if (e0 == 0) {
        float ksv = 0.f;
#pragma unroll
        for (int ch = 0; ch < 8; ch++) ksv += part2[(p * 8 + ch) * 64 + d];
        ctxA[p * 5120 + 4096 + d] = f2bf(ksv);
#pragma unroll
        for (int j = 1; j < 16; j++) ctxA[p * 5120 + 4096 + j * 64 + d] = 0;
    }
}

// out = phiQ @ [ctx | ksum]; ni=4 accumulates denominator; normalize -> bf16
__global__ __launch_bounds__(256) void attn_out_kernel(
    unsigned short* __restrict__ kv,
    const unsigned short* __restrict__ ctxA)
{
    const int p = blockIdx.x;
    const int b = p >> 3, h = p & 7;
    const int t = threadIdx.x, w = t >> 6, l = t & 63, lr = l & 15, lg = l >> 4;
    const int s0 = blockIdx.y * 256 + w * 64;
    f32x4 acc[4][5];
#pragma unroll
    for (int i = 0; i < 4; i++)
#pragma unroll
        for (int j = 0; j < 5; j++) acc[i][j] = f32x4{0.f, 0.f, 0.f, 0.f};
    const unsigned short* cb = ctxA + p * 5120;
#pragma unroll
    for (int kk = 0; kk < 2; kk++) {
        short8 af[4], bfv[5];
#pragma unroll
        for (int mi = 0; mi < 4; mi++) {
            int s = s0 + mi * 16 + lr;
            af[mi] = *(const short8*)&kv[((long)s * 8 + b) * 1024 + 512 + h * 64 + kk * 32 + lg * 8];
        }
#pragma unroll
        for (int ni = 0; ni < 5; ni++)
            bfv[ni] = *(const short8*)&cb[(ni * 16 + lr) * 64 + kk * 32 + lg * 8];
#pragma unroll
        for (int mi = 0; mi < 4; mi++)
#pragma unroll
            for (int ni = 0; ni < 5; ni++)
                acc[mi][ni] = __builtin_amdgcn_mfma_f32_16x16x32_bf16(
                    af[mi], bfv[ni], acc[mi][ni], 0, 0, 0);
    }
#pragma unroll
    for (int mi = 0; mi < 4; mi++) {
#pragma unroll
        for (int j = 0; j < 4; j++) {
            float den = __shfl(acc[mi][4][j], (l & 48));
            float rc  = 1.0f / (den + 1e-6f);
            int s = s0 + mi * 16 + lg * 4 + j;
            long base = ((long)s * 8 + b) * 1024 + h * 64;
#pragma unroll
            for (int ni = 0; ni < 4; ni++)
                kv[base + ni * 16 + lr] = f2bf(acc[mi][ni][j] * rc);
        }
    }
}

// ---------------------------------------------------------------------------
// small helpers
// ---------------------------------------------------------------------------
__global__ __launch_bounds__(256) void cvtbf_kernel(
    const float* __restrict__ x, unsigned short* __restrict__ y)
{
    long i = ((long)blockIdx.x * 256 + threadIdx.x) * 8;
    f32x4 a = *(const f32x4*)&x[i];
    f32x4 c = *(const f32x4*)&x[i + 4];
    short8 pk;
#pragma unroll
    for (int j = 0; j < 4; j++) { pk[j] = (short)f2bf(a[j]); pk[4 + j] = (short)f2bf(c[j]); }
    *(short8*)&y[i] = pk;
}

__global__ __launch_bounds__(256) void bcat_kernel(
    const float* __restrict__ bk, const float* __restrict__ bv, float* __restrict__ dst)
{
    int lyr = blockIdx.x;
    int j = blockIdx.y * 256 + threadIdx.x;
    dst[lyr * 1024 + j] = (j < 512) ? bk[lyr * 512 + j] : bv[lyr * 512 + j - 512];
}

// weight transpose + convert: Wt[n][k] = (bf16) W[k][n], per-layer strides
__global__ __launch_bounds__(256) void wconv_kernel(
    const float* __restrict__ W, unsigned short* __restrict__ Wt, int K, int N,
    long lstrW, long lstrT)
{
    __shared__ float tile[64 * 65];
    const long lz = blockIdx.z;
    const float* Wl = W + lz * lstrW;
    unsigned short* Wtl = Wt + lz * lstrT;
    const int k0 = blockIdx.x * 64, n0 = blockIdx.y * 64;
    const int t = threadIdx.x;
#pragma unroll
    for (int i = 0; i < 4; i++) {
        int q = i * 256 + t;
        int r = q >> 4, c4 = q & 15;
        f32x4 v = *(const f32x4*)&Wl[(long)(k0 + r) * N + n0 + c4 * 4];
#pragma unroll
        for (int j = 0; j < 4; j++) tile[r * 65 + c4 * 4 + j] = v[j];
    }
    __syncthreads();
#pragma unroll
    for (int i = 0; i < 4; i++) {
        int q = i * 256 + t;
        int nr = q >> 4, kc = q & 15;
        ushort4v pk;
#pragma unroll
        for (int j = 0; j < 4; j++) pk[j] = f2bf(tile[(kc * 4 + j) * 65 + nr]);
        *(ushort4v*)&Wtl[(long)(n0 + nr) * K + k0 + kc * 4] = pk;
    }
}

// ---------------------------------------------------------------------------
// Host orchestration.  ws ~121 MiB:
//  [WKV 4M][WQ 2M][WO 2M][W1 4M][W2 4M][BKV 16K][R1 32M][KV 64M][KSP][CTP 8M][CTA]
// f32 residual stream F1 = d_out (in-place RMW in gemm_ln; final LN2 leaves
// the answer there). R1 = bf16 stream copy (GEMM inputs).
// KV: {K|V} -> {ATTN|phiQ} -> HBF(64M).
// ---------------------------------------------------------------------------
extern "C" void kernel_launch(void* const* d_in, const int* in_sizes, int n_in,
                              void* d_out, int out_size, void* d_ws, size_t ws_size,
                              hipStream_t stream)
{
    const float* src  = (const float*)d_in[0];
    const float* Wq   = (const float*)d_in[1];
    const float* bq   = (const float*)d_in[2];
    const float* Wk   = (const float*)d_in[3];
    const float* bk   = (const float*)d_in[4];
    const float* Wv   = (const float*)d_in[5];
    const float* bv   = (const float*)d_in[6];
    const float* Wo   = (const float*)d_in[7];
    const float* bo   = (const float*)d_in[8];
    const float* l1g  = (const float*)d_in[9];
    const float* l1b  = (const float*)d_in[10];
    const float* W1   = (const float*)d_in[11];
    const float* b1   = (const float*)d_in[12];
    const float* W2   = (const float*)d_in[13];
    const float* b2   = (const float*)d_in[14];
    const float* l2g  = (const float*)d_in[15];
    const float* l2b  = (const float*)d_in[16];

    char* ws = (char*)d_ws;
    constexpr size_t SZ_WKV = (size_t)4 * 1024 * 512 * 2;
    constexpr size_t SZ_WQ  = (size_t)4 * 512 * 512 * 2;
    constexpr size_t SZ_WO  = SZ_WQ;
    constexpr size_t SZ_W1  = (size_t)4 * 512 * 1024 * 2;
    constexpr size_t SZ_W2  = SZ_W1;
    constexpr size_t SZ_BKV = (size_t)4 * 1024 * 4;
    constexpr size_t SZ_R1  = (size_t)32768 * 512 * 2;
    constexpr size_t SZ_KV  = (size_t)32768 * 1024 * 2;
    constexpr size_t OFF_WKV = 0;
    constexpr size_t OFF_WQ  = OFF_WKV + SZ_WKV;
    constexpr size_t OFF_WO  = OFF_WQ + SZ_WQ;
    constexpr size_t OFF_W1  = OFF_WO + SZ_WO;
    constexpr size_t OFF_W2  = OFF_W1 + SZ_W1;
    constexpr size_t OFF_BKV = OFF_W2 + SZ_W2;
    constexpr size_t OFF_R1  = OFF_BKV + SZ_BKV;
    constexpr size_t OFF_KV  = OFF_R1 + SZ_R1;
    constexpr size_t OFF_KSP = OFF_KV + SZ_KV;
    constexpr size_t OFF_CTP = OFF_KSP + (size_t)16 * 4096 * 4;
    constexpr size_t OFF_CTA = OFF_CTP + (size_t)64 * 8 * 4096 * 4;

    unsigned short* WKVT = (unsigned short*)(ws + OFF_WKV);
    unsigned short* WQT  = (unsigned short*)(ws + OFF_WQ);
    unsigned short* WOT  = (unsigned short*)(ws + OFF_WO);
    unsigned short* W1T  = (unsigned short*)(ws + OFF_W1);
    unsigned short* W2T  = (unsigned short*)(ws + OFF_W2);
    float*          BKV  = (float*)(ws + OFF_BKV);
    unsigned short* R1   = (unsigned short*)(ws + OFF_R1);
    unsigned short* KV   = (unsigned short*)(ws + OFF_KV);
    float*          KSP  = (float*)(ws + OFF_KSP);
    float*          CTP  = (float*)(ws + OFF_CTP);
    unsigned short* CTA  = (unsigned short*)(ws + OFF_CTA);
    float*          F1   = (float*)d_out;    // f32 residual stream

    dim3 blk(256);
    wconv_kernel<<<dim3(8, 8, 4),  blk, 0, stream>>>(Wk, WKVT,            512, 512, 512*512, 1024*512);
    wconv_kernel<<<dim3(8, 8, 4),  blk, 0, stream>>>(Wv, WKVT + 512*512,  512, 512, 512*512, 1024*512);
    wconv_kernel<<<dim3(8, 8, 4),  blk, 0, stream>>>(Wq, WQT,             512, 512, 512*512, 512*512);
    wconv_kernel<<<dim3(8, 8, 4),  blk, 0, stream>>>(Wo, WOT,             512, 512, 512*512, 512*512);
    wconv_kernel<<<dim3(8, 16, 4), blk, 0, stream>>>(W1, W1T,             512, 1024, 512*1024, 512*1024);
    wconv_kernel<<<dim3(16, 8, 4), blk, 0, stream>>>(W2, W2T,             1024, 512, 1024*512, 1024*512);
    bcat_kernel<<<dim3(4, 4), blk, 0, stream>>>(bk, bv, BKV);
    cvtbf_kernel<<<8192, blk, 0, stream>>>(src, R1);

    for (int lyr = 0; lyr < 4; lyr++) {
        const unsigned short* wkvt = WKVT + (size_t)lyr * 1024 * 512;
        const unsigned short* wqt  = WQT  + (size_t)lyr * 512 * 512;
        const unsigned short* wot  = WOT  + (size_t)lyr * 512 * 512;
        const unsigned short* w1t  = W1T  + (size_t)lyr * 512 * 1024;
        const unsigned short* w2t  = W2T  + (size_t)lyr * 1024 * 512;

        // K|V fused GEMM (elu on cols<512), N=1024 -> nshift=3, grid 2048
        gemm_kernel<0><<<2048, blk, 0, stream>>>(R1, 512, wkvt, BKV + lyr * 1024, KV, 1024, 3, 512);

        // ctx + ksum in one pass over KV
        ctx_partial_kernel<<<dim3(64, 8), blk, 0, stream>>>(KV, CTP, KSP);
        ctx_reduce_kernel<<<256, blk, 0, stream>>>(CTP, KSP, CTA);

        // phiQ into V slot (dead), N=512 -> nshift=2, grid 1024
        gemm_kernel<0><<<1024, blk, 0, stream>>>(R1, 512, wqt, bq + lyr * 512, KV + 512, 1024, 2, 512);
        attn_out_kernel<<<dim3(64, 16), blk, 0, stream>>>(KV, CTA);

        // Wo + residual + LN1 -> F1(f32) in-place, bf16 to R1
        const float* resp = (lyr == 0) ? src : F1;
        gemm_ln_kernel<<<256, dim3(512), 0, stream>>>(KV, 1024, wot, bo + lyr * 512, resp,
                                                      l1g + lyr * 512, l1b + lyr * 512,
                                                      F1, R1, 512);
        // FFN up + relu -> HBF (KV region, dead), N=1024 -> nshift=3
        gemm_kernel<2><<<2048, blk, 0, stream>>>(R1, 512, w1t, b1 + lyr * 1024, KV, 1024, 3, 512);
        // FFN down + residual + LN2 -> F1 in-place, bf16 to R1 (next input)
        gemm_ln_kernel<<<256, dim3(512), 0, stream>>>(KV, 1024, w2t, b2 + lyr * 512, F1,
                                                      l2g + lyr * 512, l2b + lyr * 512,
                                                      F1, R1, 1024);
    }
}